// Round 8
// baseline (979.621 us; speedup 1.0000x reference)
//
#include <hip/hip_runtime.h>
#include <hip/hip_bf16.h>

#define BATCH 4096
#define TSTEPS 80
#define VOCAB 10000
#define EDIM 100
#define UDIM 1024

// LDS: B weights 4 j x 36 s x 64 lanes x 16 B = 147456 B
//      + 8 waves x 640-half epilogue scratch = 10240 B -> 157696 B static
#define B_HALFS 73728

// s_getreg imm: hwreg(HW_REG_XCC_ID=20, offset=0, size=32) = 20 | (31<<11)
#define HWREG_XCC_ID 63508

typedef _Float16 half8 __attribute__((ext_vector_type(8)));
typedef float float4v __attribute__((ext_vector_type(4)));

// Frag-major layout: chunk(blk, kblk, lane) = 16 B holding
// row = blk*16 + (lane&15), k = kblk*32 + (lane>>4)*8 .. +8.
// h:  [mblk 256][kblk 32][lane]   Wf: [nblk 64][kblk 32][lane]
// xe: [t][mblk 256][kblk 4][lane] Wxf:[nblk 64][kblk 4][lane]

__device__ __forceinline__ void load_lds16(const void* g, void* l) {
    __builtin_amdgcn_global_load_lds(
        (const __attribute__((address_space(1))) unsigned int*)g,
        (__attribute__((address_space(3))) unsigned int*)l,
        16, 0, 0);
}

__device__ __forceinline__ float tanh_fast(float x) {
    return 1.0f - 2.0f / (__expf(2.0f * x) + 1.0f);
}

// Weight conversion only (read cross-XCD by rnn_persist -> kernel boundary
// provides visibility). blocks [0,512): Wh; [512,576): Wx.
__global__ __launch_bounds__(256) void wconv(
        const float* __restrict__ Wh, _Float16* __restrict__ Wf,
        const float* __restrict__ Wx, _Float16* __restrict__ Wxf) {
    const int bid = blockIdx.x;
    const int tid = threadIdx.x;
    if (bid < 512) {
        int cid = bid * 256 + tid;
        int lane = cid & 63, kblk = (cid >> 6) & 31, nblk = cid >> 11;
        int n = nblk * 16 + (lane & 15);
        int kb = kblk * 32 + (lane >> 4) * 8;
        half8 v;
        #pragma unroll
        for (int e = 0; e < 8; ++e) v[e] = (_Float16)Wh[(kb + e) * UDIM + n];
        *((half8*)Wf + cid) = v;
    } else {
        int cid = (bid - 512) * 256 + tid;
        int lane = cid & 63, kblk = (cid >> 6) & 3, nblk = cid >> 8;
        int n = nblk * 16 + (lane & 15);
        int kb = kblk * 32 + (lane >> 4) * 8;
        half8 v;
        #pragma unroll
        for (int e = 0; e < 8; ++e)
            v[e] = (kb + e < EDIM) ? (_Float16)Wx[(kb + e) * UDIM + n]
                                   : (_Float16)0.0f;
        *((half8*)Wxf + cid) = v;
    }
}

// Persistent kernel, 256 blocks x 512 threads (2 waves/SIMD; 157.7 KB LDS
// keeps 1 block/CU). Tile 256(M) x 64(N), waves split M only (32M x 64N).
// Step loop BYTE-IDENTICAL to the session-best R4 schedule (843-863 us):
// B pinned in LDS; B dist-2, A dist-4; rotated visit order + own-chunk regs.
// Ledger: R1 flags 1004 / R2 resident-B 895 / R3 deep-prefetch 940 /
// R5 j-split 1076 / R6 anti-phase 1177 all refuted -- do not perturb.
// NEW (this round): the xe embed-gather and hA-zero moved INTO the prologue,
// MT-LOCAL: block (mt,nt) gathers 1/16 of ITS OWN mt's xe rows (40 chains/
// thread, ILP-8) and zeroes hA[mblk=mt*16+nt]. Readers of that data are the
// 16 same-mt blocks -- on ONE XCD in fast mode -- so the existing barg
// startup barrier (posted after a vmcnt-draining __syncthreads) is the only
// sync needed: same L2-locality mechanism as the per-step h exchange.
// B-staging is issued before the barg spin (overlaps straggler wait).
// Fallback (!fast): one extra fenced global barrier (release + barg2 +
// acquire) makes cross-XCD xe/hA visible; slow path stays correct.
__global__ __launch_bounds__(512, 2) void rnn_persist(
        _Float16* __restrict__ hA, _Float16* __restrict__ hB,
        _Float16* __restrict__ xe,
        const _Float16* __restrict__ Wf, const _Float16* __restrict__ Wxf,
        const float* __restrict__ bias,
        const int* __restrict__ inputs, const float* __restrict__ emb,
        unsigned* vote, unsigned* barg, unsigned* bar, unsigned* fbar)
{
    __shared__ __align__(16) _Float16 smem[B_HALFS + 8 * 640];  // 157696 B
    __shared__ unsigned sFast;

    const int tid  = threadIdx.x;
    const int lane = tid & 63, wave = tid >> 6;
    const int bid  = blockIdx.x;
    const int mt = bid & 15, nt = bid >> 4;
    const int lrow = lane & 15, lq = lane >> 4;

    // ---- Prologue 1: mt-local embed gather. 40 chains/thread, ILP-8.
    //      f in [nt*20480, nt*20480+20480): lane=f&63, kblk=(f>>6)&3,
    //      ml=(f>>8)&15, t=f>>12 -> covers all cids of stripe mt.
    {
        const int fbase = nt * 20480 + tid;
        #pragma unroll 1
        for (int k = 0; k < 40; k += 8) {
            const float* gsrc[8];
            int gkb[8], gcid[8];
            #pragma unroll
            for (int u = 0; u < 8; ++u) {
                int f = fbase + (k + u) * 512;
                int lane_ = f & 63, kblk_ = (f >> 6) & 3;
                int ml = (f >> 8) & 15, t_ = f >> 12;
                int mb = mt * 16 + ml;
                gcid[u] = (t_ << 16) | (mb << 8) | (kblk_ << 6) | lane_;
                gkb[u] = kblk_ * 32 + (lane_ >> 4) * 8;
                int m = mb * 16 + (lane_ & 15);
                gsrc[u] = emb + (size_t)inputs[m * TSTEPS + t_] * EDIM;
            }
            #pragma unroll
            for (int u = 0; u < 8; ++u) {
                half8 v;
                #pragma unroll
                for (int e = 0; e < 8; ++e)
                    v[e] = (gkb[u] + e < EDIM) ? (_Float16)gsrc[u][gkb[u] + e]
                                               : (_Float16)0.0f;
                *((half8*)xe + gcid[u]) = v;
            }
        }
    }
    // ---- Prologue 2: zero hA slice mblk = mt*16 + nt (f>>11 == nt) ----
    {
        half8 z;
        #pragma unroll
        for (int e = 0; e < 8; ++e) z[e] = (_Float16)0.0f;
        #pragma unroll
        for (int k = 0; k < 4; ++k) {
            int f = k * 512 + tid;
            int lane_ = f & 63, kblk_ = f >> 6;       // kblk in [0,32)
            *((half8*)hA + ((size_t)((mt * 16 + nt) * 32 + kblk_) * 64 + lane_)) = z;
        }
    }
    __syncthreads();   // drains all waves' gather/zero stores (vmcnt)

    // ---- B-staging issued now: overlaps the barg straggler wait ----
    if (wave < 4) {
        const half8* wx8 = (const half8*)Wxf;
        const half8* wh8 = (const half8*)Wf;
        #pragma unroll 1
        for (int s = 0; s < 36; ++s) {
            const half8* src = (s < 4)
                ? wx8 + ((size_t)(nt * 4 + wave) * 4 + s) * 64 + lane
                : wh8 + ((size_t)(nt * 4 + wave) * 32 + (s - 4)) * 64 + lane;
            load_lds16(src, smem + ((wave * 36 + s) * 64 + lane) * 8);
        }
    }

    // ---- XCD-locality vote + one global barrier (doubles as prep-done) ----
    if (tid == 0) {
        unsigned xcd = ((unsigned)__builtin_amdgcn_s_getreg(HWREG_XCC_ID)) & 7u;
        __hip_atomic_fetch_or(&vote[mt], 1u << xcd, __ATOMIC_RELAXED,
                              __HIP_MEMORY_SCOPE_AGENT);
        __builtin_amdgcn_s_waitcnt(0);
        __hip_atomic_fetch_add(barg, 1u, __ATOMIC_RELAXED, __HIP_MEMORY_SCOPE_AGENT);
        while (__hip_atomic_load(barg, __ATOMIC_RELAXED,
                                 __HIP_MEMORY_SCOPE_AGENT) < 256u)
            __builtin_amdgcn_s_sleep(1);
        unsigned allv = 0u, own = 0u;
        for (int g = 0; g < 16; ++g) {
            unsigned v = __hip_atomic_load(&vote[g], __ATOMIC_RELAXED,
                                           __HIP_MEMORY_SCOPE_AGENT);
            allv |= v;
            if (g == mt) own = v;
        }
        const bool single = own != 0u && (own & (own - 1u)) == 0u;
        sFast = (single && __popc(allv) == 8) ? 1u : 0u;
    }
    __syncthreads();
    const bool fast = sFast != 0u;

    // ---- Fallback only: fenced barrier makes cross-XCD xe/hA visible ----
    if (!fast) {
        if (tid == 0) {
            __builtin_amdgcn_fence(__ATOMIC_RELEASE, "agent");
            __hip_atomic_fetch_add(barg + 1, 1u, __ATOMIC_RELAXED,
                                   __HIP_MEMORY_SCOPE_AGENT);
            while (__hip_atomic_load(barg + 1, __ATOMIC_RELAXED,
                                     __HIP_MEMORY_SCOPE_AGENT) < 256u)
                __builtin_amdgcn_s_sleep(1);
            __builtin_amdgcn_fence(__ATOMIC_ACQUIRE, "agent");
        }
        __syncthreads();
    }
    __syncthreads();   // B-staging (global_load_lds) complete before use

    _Float16* tb = smem + B_HALFS + wave * 640;   // epilogue scratch, wave-private

    float bj[4];
    #pragma unroll
    for (int j = 0; j < 4; ++j) bj[j] = bias[nt * 64 + j * 16 + lrow];

    int mblk[2];                                  // wave tile: 32 M rows
    #pragma unroll
    for (int i = 0; i < 2; ++i) mblk[i] = mt * 16 + wave * 2 + i;

    unsigned* mybar = bar + mt * 32;              // fallback single counter
    unsigned* mycnt = fbar + (mt * 16 + nt) * 4;  // own producer counter (16 B stride)

    const int cb = nt * 2;                        // rotated chunk base

#define LDB(bf, s) { _Pragma("unroll") \
    for (int j = 0; j < 4; ++j) \
        bf[j] = *(const half8*)&smem[(((j) * 36 + (s)) * 64 + lane) * 8]; }
#define LDBR(bf, v) { const int s_ = 4 + ((cb + (v)) & 31); _Pragma("unroll") \
    for (int j = 0; j < 4; ++j) \
        bf[j] = *(const half8*)&smem[((j * 36 + s_) * 64 + lane) * 8]; }
#define FMAB(A, B) { _Pragma("unroll") \
    for (int i = 0; i < 2; ++i) { _Pragma("unroll") \
        for (int j = 0; j < 4; ++j) \
            acc[i][j] = __builtin_amdgcn_mfma_f32_16x16x32_f16(A[i], B[j], acc[i][j], 0, 0, 0); } }
#define LDHR(A, v) { const int c_ = (cb + (v)) & 31; _Pragma("unroll") \
    for (int i = 0; i < 2; ++i) A[i] = pah[i][c_ * 64]; }
#define ZACC { _Pragma("unroll") \
    for (int i = 0; i < 2; ++i) { _Pragma("unroll") \
        for (int j = 0; j < 4; ++j) { acc[i][j][0]=0.f; acc[i][j][1]=0.f; acc[i][j][2]=0.f; acc[i][j][3]=0.f; } } }

    float4v acc[2][4];
    half8 a0[2], a1[2], a2[2], a3[2], b0[4], b1[4];
    half8 own0[2], own1[2];                       // own chunks (visits 0,1); h(0)=0
    #pragma unroll
    for (int e = 0; e < 8; ++e) {
        own0[0][e] = (_Float16)0.0f; own0[1][e] = (_Float16)0.0f;
        own1[0][e] = (_Float16)0.0f; own1[1][e] = (_Float16)0.0f;
    }

    // x-segment for a step: acc += xe_tn @ Wx  (B slices 0..3)
    auto xfma = [&](int tn) {
        const half8* xe8 = (const half8*)xe + (size_t)tn * 65536;
        #pragma unroll
        for (int i = 0; i < 2; ++i) {
            const half8* px = xe8 + (size_t)mblk[i] * 4 * 64 + lane;
            a0[i] = px[0]; a1[i] = px[64]; a2[i] = px[128]; a3[i] = px[192];
        }
        LDB(b0, 0); LDB(b1, 1);
        FMAB(a0, b0); LDB(b0, 2);
        FMAB(a1, b1); LDB(b1, 3);
        FMAB(a2, b0);
        FMAB(a3, b1);
    };

    ZACC;
    xfma(0);

    #pragma unroll 1
    for (int t = 0; t < TSTEPS; ++t) {
        const _Float16* hi = (t & 1) ? hB : hA;
        _Float16*       ho = (t & 1) ? hA : hB;

        const half8* pah[2];
        #pragma unroll
        for (int i = 0; i < 2; ++i)
            pah[i] = (const half8*)hi + (size_t)mblk[i] * 32 * 64 + lane;

        // ---- h-loop: 32 visits, rotated order chunk=(2nt+v)&31.
        //      Visits 0,1 = own chunks from registers (no load, no latency).
        //      A dist-4 (a2,a3 then loop-carried), B dist-2 (r0 schedule).
        #pragma unroll
        for (int i = 0; i < 2; ++i) { a0[i] = own0[i]; a1[i] = own1[i]; }
        LDHR(a2, 2); LDHR(a3, 3);
        LDBR(b0, 0); LDBR(b1, 1);
        #pragma unroll 1
        for (int v = 0; v < 28; v += 4) {
            FMAB(a0, b0); LDBR(b0, v + 2); LDHR(a0, v + 4);
            FMAB(a1, b1); LDBR(b1, v + 3); LDHR(a1, v + 5);
            FMAB(a2, b0); LDBR(b0, v + 4); LDHR(a2, v + 6);
            FMAB(a3, b1); LDBR(b1, v + 5); LDHR(a3, v + 7);
        }
        // tail: visits 28..31
        FMAB(a0, b0); LDBR(b0, 30);
        FMAB(a1, b1); LDBR(b1, 31);
        FMAB(a2, b0);
        FMAB(a3, b1);

        // ---- Epilogue: tanh + C-layout -> A-layout (wave-private LDS) ----
        #pragma unroll
        for (int i = 0; i < 2; ++i) {
            #pragma unroll
            for (int jp = 0; jp < 2; ++jp) {
                #pragma unroll
                for (int jj = 0; jj < 2; ++jj) {
                    const int j = jp * 2 + jj;
                    #pragma unroll
                    for (int r = 0; r < 4; ++r)
                        tb[(lq * 4 + r) * 40 + jj * 16 + lrow] =
                            (_Float16)tanh_fast(acc[i][j][r] + bj[j]);
                }
                // same-wave LDS RAW -> lgkmcnt only, no barrier
                half8 v = *(const half8*)&tb[lrow * 40 + lq * 8];
                if (jp == 0) own0[i] = v; else own1[i] = v;   // keep own chunks
                *((half8*)ho + (size_t)(mblk[i] * 32 + nt * 2 + jp) * 64 + lane) = v;
            }
        }

        // ---- x-segment of step t+1 (independent of h_{t+1}) BEFORE barrier ----
        if (t < TSTEPS - 1) {
            ZACC;
            xfma(t + 1);
            __syncthreads();    // drains all waves' h stores to L2
            if (fast) {
                // distributed barrier: parallel RMWs + 16-lane parallel spin
                if (tid == 0)
                    __hip_atomic_fetch_add(mycnt, 1u, __ATOMIC_RELAXED,
                                           __HIP_MEMORY_SCOPE_AGENT);
                if (tid < 16) {
                    while (__hip_atomic_load(&fbar[(mt * 16 + tid) * 4],
                                             __ATOMIC_RELAXED,
                                             __HIP_MEMORY_SCOPE_AGENT)
                           < (unsigned)(t + 1))
                        __builtin_amdgcn_s_sleep(1);
                }
            } else if (tid == 0) {
                __builtin_amdgcn_fence(__ATOMIC_RELEASE, "agent");
                __hip_atomic_fetch_add(mybar, 1u, __ATOMIC_RELAXED,
                                       __HIP_MEMORY_SCOPE_AGENT);
                const unsigned target = 16u * (unsigned)(t + 1);
                while (__hip_atomic_load(mybar, __ATOMIC_RELAXED,
                                         __HIP_MEMORY_SCOPE_AGENT) < target)
                    __builtin_amdgcn_s_sleep(1);
                __builtin_amdgcn_fence(__ATOMIC_ACQUIRE, "agent");
            }
            __syncthreads();
        }
    }
#undef LDB
#undef LDBR
#undef FMAB
#undef LDHR
#undef ZACC
}

// out[b] = h[b,:].Wo + bo, h frag-major
__global__ __launch_bounds__(256) void out_proj(const _Float16* __restrict__ h,
                                                const float* __restrict__ Wo,
                                                const float* __restrict__ bo,
                                                float* __restrict__ out) {
    const int lane = threadIdx.x & 63;
    const int wave = threadIdx.x >> 6;
    const int row = blockIdx.x * 4 + wave;
    const int mblk = row >> 4, lb = row & 15;
    const half8* hf = (const half8*)h;
    float s = 0.0f;
    #pragma unroll
    for (int c = 0; c < 2; ++c) {
        const int kblk = lane >> 1;
        const int q = (lane & 1) * 2 + c;
        half8 v = hf[(size_t)(mblk * 32 + kblk) * 64 + lb + q * 16];
        const int k0 = kblk * 32 + q * 8;
        #pragma unroll
        for (int e = 0; e < 8; ++e) s += (float)v[e] * Wo[k0 + e];
    }
    #pragma unroll
    for (int off = 32; off > 0; off >>= 1) s += __shfl_down(s, off, 64);
    if (lane == 0) out[row] = s + bo[0];
}

extern "C" void kernel_launch(void* const* d_in, const int* in_sizes, int n_in,
                              void* d_out, int out_size, void* d_ws, size_t ws_size,
                              hipStream_t stream) {
    const int*   inputs = (const int*)  d_in[0];
    const float* emb    = (const float*)d_in[1];
    const float* Wx     = (const float*)d_in[2];
    const float* Wh     = (const float*)d_in[3];
    const float* b      = (const float*)d_in[4];
    const float* Wo     = (const float*)d_in[5];
    const float* bo     = (const float*)d_in[6];
    float* out = (float*)d_out;

    char* ws = (char*)d_ws;
    _Float16* Wf   = (_Float16*)ws;                          // 2 MB
    _Float16* Wxf  = (_Float16*)(ws + (2u  << 20));          // 256 KB
    _Float16* hA   = (_Float16*)(ws + (3u  << 20));          // 8 MB
    _Float16* hB   = (_Float16*)(ws + (11u << 20));          // 8 MB
    _Float16* xe   = (_Float16*)(ws + (19u << 20));          // 84 MB
    unsigned* vote = (unsigned*)(ws + (103u << 20));         // 16 u32
    unsigned* barg = vote + 16;                              // 2 u32 (barg, barg2)
    unsigned* bar  = vote + 256;                             // 16 x 32-u32 (fallback)
    unsigned* fbar = vote + 1024;                            // 16 x 16 x 4-u32 (fast)

    hipMemsetAsync(vote, 0, 16384, stream);
    wconv<<<dim3(576), dim3(256), 0, stream>>>(Wh, Wf, Wx, Wxf);

    // Gather + hA-zero now inside rnn_persist's prologue (mt-local, covered
    // by the startup barrier; no extra kernel, no fences in fast mode).
    rnn_persist<<<dim3(256), dim3(512), 0, stream>>>(hA, hB, xe, Wf, Wxf, b,
                                                     inputs, emb,
                                                     vote, barg, bar, fbar);

    // T=80 even -> final h in hA
    out_proj<<<dim3(1024), dim3(256), 0, stream>>>(hA, Wo, bo, out);
}

// Round 11
// 896.154 us; speedup vs baseline: 1.0931x; 1.0931x over previous
//
#include <hip/hip_runtime.h>
#include <hip/hip_bf16.h>

#define BATCH 4096
#define TSTEPS 80
#define VOCAB 10000
#define EDIM 100
#define UDIM 1024

// LDS: B weights 4 j x 36 s x 64 lanes x 16 B = 147456 B
//      + 8 waves x 640-half epilogue scratch = 10240 B -> 157696 B static
#define B_HALFS 73728

// s_getreg imm: hwreg(HW_REG_XCC_ID=20, offset=0, size=32) = 20 | (31<<11)
#define HWREG_XCC_ID 63508

typedef _Float16 half8 __attribute__((ext_vector_type(8)));
typedef float float4v __attribute__((ext_vector_type(4)));

// Frag-major layout: chunk(blk, kblk, lane) = 16 B holding
// row = blk*16 + (lane&15), k = kblk*32 + (lane>>4)*8 .. +8.
// h:  [mblk 256][kblk 32][lane]   Wf: [nblk 64][kblk 32][lane]
// xe: [t][mblk 256][kblk 4][lane] Wxf:[nblk 64][kblk 4][lane]

__device__ __forceinline__ void load_lds16(const void* g, void* l) {
    __builtin_amdgcn_global_load_lds(
        (const __attribute__((address_space(1))) unsigned int*)g,
        (__attribute__((address_space(3))) unsigned int*)l,
        16, 0, 0);
}

__device__ __forceinline__ float tanh_fast(float x) {
    return 1.0f - 2.0f / (__expf(2.0f * x) + 1.0f);
}

// Weight conversion only (read cross-XCD by rnn_persist -> kernel boundary
// provides visibility). blocks [0,512): Wh; [512,576): Wx.
__global__ __launch_bounds__(256) void wconv(
        const float* __restrict__ Wh, _Float16* __restrict__ Wf,
        const float* __restrict__ Wx, _Float16* __restrict__ Wxf) {
    const int bid = blockIdx.x;
    const int tid = threadIdx.x;
    if (bid < 512) {
        int cid = bid * 256 + tid;
        int lane = cid & 63, kblk = (cid >> 6) & 31, nblk = cid >> 11;
        int n = nblk * 16 + (lane & 15);
        int kb = kblk * 32 + (lane >> 4) * 8;
        half8 v;
        #pragma unroll
        for (int e = 0; e < 8; ++e) v[e] = (_Float16)Wh[(kb + e) * UDIM + n];
        *((half8*)Wf + cid) = v;
    } else {
        int cid = (bid - 512) * 256 + tid;
        int lane = cid & 63, kblk = (cid >> 6) & 3, nblk = cid >> 8;
        int n = nblk * 16 + (lane & 15);
        int kb = kblk * 32 + (lane >> 4) * 8;
        half8 v;
        #pragma unroll
        for (int e = 0; e < 8; ++e)
            v[e] = (kb + e < EDIM) ? (_Float16)Wx[(kb + e) * UDIM + n]
                                   : (_Float16)0.0f;
        *((half8*)Wxf + cid) = v;
    }
}

// Persistent kernel, 256 blocks x 512 threads (2 waves/SIMD; 157.7 KB LDS
// keeps 1 block/CU). Tile 256(M) x 64(N), waves split M only (32M x 64N).
// Step loop BYTE-IDENTICAL to the session-best R4/R7 schedule (843 us):
// B pinned in LDS; B dist-2, A dist-4; rotated visit order + own-chunk regs.
// Ledger: R1 flags 1004 / R2 resident-B 895 / R3 deep-prefetch 940 /
// R5 j-split 1076 / R6 anti-phase 1177 / R8 bulk-prologue-gather 949 --
// all refuted; do not perturb the h-loop.
// R9/R10 failed at container acquisition (no timing fields -> kernel never
// ran); design resubmitted unchanged. R8's mt-local gather idea with the
// placement fixed -- AMORTIZED over the 80 steps in the barrier-slack
// window. Per step, block (mt,nt) gathers xe of ITS OWN mblk (= mt*16+nt)
// for step t+3: 256 chains (tid<256, one 2-level chain each) issued between
// the first __syncthreads and the flag spin, where waves otherwise idle on
// stragglers. DISTANCE-3 makes visibility free: stores drain at step t's
// second __syncthreads; the flag value t+2 (posted end of step t+1, after
// that drain) is what consumers wait on before reading xe[t+3] at the end
// of step t+2 -- one full flag exchange after the drain, same mt-local/
// XCD-local mechanism as the per-step h exchange (fenced fallback path
// covers cross-XCD the same way; R8 validated this chain end-to-end on HW).
// Prologue gathers only t=0,1,2 (3 chains, ILP-3) + zeroes hA slice.
__global__ __launch_bounds__(512, 2) void rnn_persist(
        _Float16* __restrict__ hA, _Float16* __restrict__ hB,
        _Float16* __restrict__ xe,
        const _Float16* __restrict__ Wf, const _Float16* __restrict__ Wxf,
        const float* __restrict__ bias,
        const int* __restrict__ inputs, const float* __restrict__ emb,
        unsigned* vote, unsigned* barg, unsigned* bar, unsigned* fbar)
{
    __shared__ __align__(16) _Float16 smem[B_HALFS + 8 * 640];  // 157696 B
    __shared__ unsigned sFast;

    const int tid  = threadIdx.x;
    const int lane = tid & 63, wave = tid >> 6;
    const int bid  = blockIdx.x;
    const int mt = bid & 15, nt = bid >> 4;
    const int lrow = lane & 15, lq = lane >> 4;

    // Gather geometry (tid<256 only): this block's own mblk, one chain/t.
    const int gmb   = mt * 16 + nt;
    const int glane = tid & 63;
    const int gkblk = tid >> 6;                    // [0,4) for tid<256
    const int gkb   = gkblk * 32 + ((glane >> 4) << 3);
    const int gm    = gmb * 16 + (glane & 15);

    // ---- Prologue 1: gather xe for t = 0,1,2 (ILP-3) ----
    if (tid < 256) {
        const float* src[3];
        #pragma unroll
        for (int u = 0; u < 3; ++u)
            src[u] = emb + (size_t)inputs[gm * TSTEPS + u] * EDIM;
        #pragma unroll
        for (int u = 0; u < 3; ++u) {
            half8 v;
            #pragma unroll
            for (int e = 0; e < 8; ++e)
                v[e] = (gkb + e < EDIM) ? (_Float16)src[u][gkb + e]
                                        : (_Float16)0.0f;
            *((half8*)xe + ((u << 16) | (gmb << 8) | (gkblk << 6) | glane)) = v;
        }
    }
    // ---- Prologue 2: zero hA slice mblk = mt*16 + nt ----
    {
        half8 z;
        #pragma unroll
        for (int e = 0; e < 8; ++e) z[e] = (_Float16)0.0f;
        #pragma unroll
        for (int k = 0; k < 4; ++k) {
            int f = k * 512 + tid;
            int lane_ = f & 63, kblk_ = f >> 6;       // kblk in [0,32)
            *((half8*)hA + ((size_t)((mt * 16 + nt) * 32 + kblk_) * 64 + lane_)) = z;
        }
    }
    __syncthreads();   // drains all waves' gather/zero stores (vmcnt)

    // ---- B-staging issued now: overlaps the barg straggler wait ----
    if (wave < 4) {
        const half8* wx8 = (const half8*)Wxf;
        const half8* wh8 = (const half8*)Wf;
        #pragma unroll 1
        for (int s = 0; s < 36; ++s) {
            const half8* src = (s < 4)
                ? wx8 + ((size_t)(nt * 4 + wave) * 4 + s) * 64 + lane
                : wh8 + ((size_t)(nt * 4 + wave) * 32 + (s - 4)) * 64 + lane;
            load_lds16(src, smem + ((wave * 36 + s) * 64 + lane) * 8);
        }
    }

    // ---- XCD-locality vote + one global barrier (doubles as prep-done) ----
    if (tid == 0) {
        unsigned xcd = ((unsigned)__builtin_amdgcn_s_getreg(HWREG_XCC_ID)) & 7u;
        __hip_atomic_fetch_or(&vote[mt], 1u << xcd, __ATOMIC_RELAXED,
                              __HIP_MEMORY_SCOPE_AGENT);
        __builtin_amdgcn_s_waitcnt(0);
        __hip_atomic_fetch_add(barg, 1u, __ATOMIC_RELAXED, __HIP_MEMORY_SCOPE_AGENT);
        while (__hip_atomic_load(barg, __ATOMIC_RELAXED,
                                 __HIP_MEMORY_SCOPE_AGENT) < 256u)
            __builtin_amdgcn_s_sleep(1);
        unsigned allv = 0u, own = 0u;
        for (int g = 0; g < 16; ++g) {
            unsigned v = __hip_atomic_load(&vote[g], __ATOMIC_RELAXED,
                                           __HIP_MEMORY_SCOPE_AGENT);
            allv |= v;
            if (g == mt) own = v;
        }
        const bool single = own != 0u && (own & (own - 1u)) == 0u;
        sFast = (single && __popc(allv) == 8) ? 1u : 0u;
    }
    __syncthreads();
    const bool fast = sFast != 0u;

    // ---- Fallback only: fenced barrier makes cross-XCD xe/hA visible ----
    if (!fast) {
        if (tid == 0) {
            __builtin_amdgcn_fence(__ATOMIC_RELEASE, "agent");
            __hip_atomic_fetch_add(barg + 1, 1u, __ATOMIC_RELAXED,
                                   __HIP_MEMORY_SCOPE_AGENT);
            while (__hip_atomic_load(barg + 1, __ATOMIC_RELAXED,
                                     __HIP_MEMORY_SCOPE_AGENT) < 256u)
                __builtin_amdgcn_s_sleep(1);
            __builtin_amdgcn_fence(__ATOMIC_ACQUIRE, "agent");
        }
        __syncthreads();
    }
    __syncthreads();   // B-staging (global_load_lds) complete before use

    _Float16* tb = smem + B_HALFS + wave * 640;   // epilogue scratch, wave-private

    float bj[4];
    #pragma unroll
    for (int j = 0; j < 4; ++j) bj[j] = bias[nt * 64 + j * 16 + lrow];

    int mblk[2];                                  // wave tile: 32 M rows
    #pragma unroll
    for (int i = 0; i < 2; ++i) mblk[i] = mt * 16 + wave * 2 + i;

    unsigned* mybar = bar + mt * 32;              // fallback single counter
    unsigned* mycnt = fbar + (mt * 16 + nt) * 4;  // own producer counter (16 B stride)

    const int cb = nt * 2;                        // rotated chunk base

#define LDB(bf, s) { _Pragma("unroll") \
    for (int j = 0; j < 4; ++j) \
        bf[j] = *(const half8*)&smem[(((j) * 36 + (s)) * 64 + lane) * 8]; }
#define LDBR(bf, v) { const int s_ = 4 + ((cb + (v)) & 31); _Pragma("unroll") \
    for (int j = 0; j < 4; ++j) \
        bf[j] = *(const half8*)&smem[((j * 36 + s_) * 64 + lane) * 8]; }
#define FMAB(A, B) { _Pragma("unroll") \
    for (int i = 0; i < 2; ++i) { _Pragma("unroll") \
        for (int j = 0; j < 4; ++j) \
            acc[i][j] = __builtin_amdgcn_mfma_f32_16x16x32_f16(A[i], B[j], acc[i][j], 0, 0, 0); } }
#define LDHR(A, v) { const int c_ = (cb + (v)) & 31; _Pragma("unroll") \
    for (int i = 0; i < 2; ++i) A[i] = pah[i][c_ * 64]; }
#define ZACC { _Pragma("unroll") \
    for (int i = 0; i < 2; ++i) { _Pragma("unroll") \
        for (int j = 0; j < 4; ++j) { acc[i][j][0]=0.f; acc[i][j][1]=0.f; acc[i][j][2]=0.f; acc[i][j][3]=0.f; } } }

    float4v acc[2][4];
    half8 a0[2], a1[2], a2[2], a3[2], b0[4], b1[4];
    half8 own0[2], own1[2];                       // own chunks (visits 0,1); h(0)=0
    #pragma unroll
    for (int e = 0; e < 8; ++e) {
        own0[0][e] = (_Float16)0.0f; own0[1][e] = (_Float16)0.0f;
        own1[0][e] = (_Float16)0.0f; own1[1][e] = (_Float16)0.0f;
    }

    // Amortized gather: one chain for step t+3, in the barrier-slack window.
    auto gather3 = [&](int t) {
        if (tid < 256 && t < TSTEPS - 3) {
            const int tg = t + 3;
            const int tok = inputs[gm * TSTEPS + tg];
            const float* src = emb + (size_t)tok * EDIM;
            half8 v;
            #pragma unroll
            for (int e = 0; e < 8; ++e)
                v[e] = (gkb + e < EDIM) ? (_Float16)src[gkb + e]
                                        : (_Float16)0.0f;
            *((half8*)xe + ((tg << 16) | (gmb << 8) | (gkblk << 6) | glane)) = v;
        }
    };

    // x-segment for a step: acc += xe_tn @ Wx  (B slices 0..3)
    auto xfma = [&](int tn) {
        const half8* xe8 = (const half8*)xe + (size_t)tn * 65536;
        #pragma unroll
        for (int i = 0; i < 2; ++i) {
            const half8* px = xe8 + (size_t)mblk[i] * 4 * 64 + lane;
            a0[i] = px[0]; a1[i] = px[64]; a2[i] = px[128]; a3[i] = px[192];
        }
        LDB(b0, 0); LDB(b1, 1);
        FMAB(a0, b0); LDB(b0, 2);
        FMAB(a1, b1); LDB(b1, 3);
        FMAB(a2, b0);
        FMAB(a3, b1);
    };

    ZACC;
    xfma(0);

    #pragma unroll 1
    for (int t = 0; t < TSTEPS; ++t) {
        const _Float16* hi = (t & 1) ? hB : hA;
        _Float16*       ho = (t & 1) ? hA : hB;

        const half8* pah[2];
        #pragma unroll
        for (int i = 0; i < 2; ++i)
            pah[i] = (const half8*)hi + (size_t)mblk[i] * 32 * 64 + lane;

        // ---- h-loop: 32 visits, rotated order chunk=(2nt+v)&31.
        //      Visits 0,1 = own chunks from registers (no load, no latency).
        //      A dist-4 (a2,a3 then loop-carried), B dist-2 (r0 schedule).
        #pragma unroll
        for (int i = 0; i < 2; ++i) { a0[i] = own0[i]; a1[i] = own1[i]; }
        LDHR(a2, 2); LDHR(a3, 3);
        LDBR(b0, 0); LDBR(b1, 1);
        #pragma unroll 1
        for (int v = 0; v < 28; v += 4) {
            FMAB(a0, b0); LDBR(b0, v + 2); LDHR(a0, v + 4);
            FMAB(a1, b1); LDBR(b1, v + 3); LDHR(a1, v + 5);
            FMAB(a2, b0); LDBR(b0, v + 4); LDHR(a2, v + 6);
            FMAB(a3, b1); LDBR(b1, v + 5); LDHR(a3, v + 7);
        }
        // tail: visits 28..31
        FMAB(a0, b0); LDBR(b0, 30);
        FMAB(a1, b1); LDBR(b1, 31);
        FMAB(a2, b0);
        FMAB(a3, b1);

        // ---- Epilogue: tanh + C-layout -> A-layout (wave-private LDS) ----
        #pragma unroll
        for (int i = 0; i < 2; ++i) {
            #pragma unroll
            for (int jp = 0; jp < 2; ++jp) {
                #pragma unroll
                for (int jj = 0; jj < 2; ++jj) {
                    const int j = jp * 2 + jj;
                    #pragma unroll
                    for (int r = 0; r < 4; ++r)
                        tb[(lq * 4 + r) * 40 + jj * 16 + lrow] =
                            (_Float16)tanh_fast(acc[i][j][r] + bj[j]);
                }
                // same-wave LDS RAW -> lgkmcnt only, no barrier
                half8 v = *(const half8*)&tb[lrow * 40 + lq * 8];
                if (jp == 0) own0[i] = v; else own1[i] = v;   // keep own chunks
                *((half8*)ho + (size_t)(mblk[i] * 32 + nt * 2 + jp) * 64 + lane) = v;
            }
        }

        // ---- x-segment of step t+1 (independent of h_{t+1}) BEFORE barrier ----
        if (t < TSTEPS - 1) {
            ZACC;
            xfma(t + 1);
            __syncthreads();    // drains all waves' h stores to L2
            if (fast) {
                // distributed barrier: parallel RMWs + 16-lane parallel spin.
                // gather3 rides in the straggler-wait slack; its stores drain
                // at the second __syncthreads, one flag exchange before use.
                if (tid == 0)
                    __hip_atomic_fetch_add(mycnt, 1u, __ATOMIC_RELAXED,
                                           __HIP_MEMORY_SCOPE_AGENT);
                gather3(t);
                if (tid < 16) {
                    while (__hip_atomic_load(&fbar[(mt * 16 + tid) * 4],
                                             __ATOMIC_RELAXED,
                                             __HIP_MEMORY_SCOPE_AGENT)
                           < (unsigned)(t + 1))
                        __builtin_amdgcn_s_sleep(1);
                }
            } else {
                gather3(t);
                if (tid == 0) {
                    __builtin_amdgcn_fence(__ATOMIC_RELEASE, "agent");
                    __hip_atomic_fetch_add(mybar, 1u, __ATOMIC_RELAXED,
                                           __HIP_MEMORY_SCOPE_AGENT);
                    const unsigned target = 16u * (unsigned)(t + 1);
                    while (__hip_atomic_load(mybar, __ATOMIC_RELAXED,
                                             __HIP_MEMORY_SCOPE_AGENT) < target)
                        __builtin_amdgcn_s_sleep(1);
                    __builtin_amdgcn_fence(__ATOMIC_ACQUIRE, "agent");
                }
            }
            __syncthreads();
        }
    }
#undef LDB
#undef LDBR
#undef FMAB
#undef LDHR
#undef ZACC
}

// out[b] = h[b,:].Wo + bo, h frag-major
__global__ __launch_bounds__(256) void out_proj(const _Float16* __restrict__ h,
                                                const float* __restrict__ Wo,
                                                const float* __restrict__ bo,
                                                float* __restrict__ out) {
    const int lane = threadIdx.x & 63;
    const int wave = threadIdx.x >> 6;
    const int row = blockIdx.x * 4 + wave;
    const int mblk = row >> 4, lb = row & 15;
    const half8* hf = (const half8*)h;
    float s = 0.0f;
    #pragma unroll
    for (int c = 0; c < 2; ++c) {
        const int kblk = lane >> 1;
        const int q = (lane & 1) * 2 + c;
        half8 v = hf[(size_t)(mblk * 32 + kblk) * 64 + lb + q * 16];
        const int k0 = kblk * 32 + q * 8;
        #pragma unroll
        for (int e = 0; e < 8; ++e) s += (float)v[e] * Wo[k0 + e];
    }
    #pragma unroll
    for (int off = 32; off > 0; off >>= 1) s += __shfl_down(s, off, 64);
    if (lane == 0) out[row] = s + bo[0];
}

extern "C" void kernel_launch(void* const* d_in, const int* in_sizes, int n_in,
                              void* d_out, int out_size, void* d_ws, size_t ws_size,
                              hipStream_t stream) {
    const int*   inputs = (const int*)  d_in[0];
    const float* emb    = (const float*)d_in[1];
    const float* Wx     = (const float*)d_in[2];
    const float* Wh     = (const float*)d_in[3];
    const float* b      = (const float*)d_in[4];
    const float* Wo     = (const float*)d_in[5];
    const float* bo     = (const float*)d_in[6];
    float* out = (float*)d_out;

    char* ws = (char*)d_ws;
    _Float16* Wf   = (_Float16*)ws;                          // 2 MB
    _Float16* Wxf  = (_Float16*)(ws + (2u  << 20));          // 256 KB
    _Float16* hA   = (_Float16*)(ws + (3u  << 20));          // 8 MB
    _Float16* hB   = (_Float16*)(ws + (11u << 20));          // 8 MB
    _Float16* xe   = (_Float16*)(ws + (19u << 20));          // 84 MB
    unsigned* vote = (unsigned*)(ws + (103u << 20));         // 16 u32
    unsigned* barg = vote + 16;                              // 2 u32 (barg, barg2)
    unsigned* bar  = vote + 256;                             // 16 x 32-u32 (fallback)
    unsigned* fbar = vote + 1024;                            // 16 x 16 x 4-u32 (fast)

    hipMemsetAsync(vote, 0, 16384, stream);
    wconv<<<dim3(576), dim3(256), 0, stream>>>(Wh, Wf, Wx, Wxf);

    // Gather amortized inside rnn_persist (prologue t=0..2; in-step t+3).
    rnn_persist<<<dim3(256), dim3(512), 0, stream>>>(hA, hB, xe, Wf, Wxf, b,
                                                     inputs, emb,
                                                     vote, barg, bar, fbar);

    // T=80 even -> final h in hA
    out_proj<<<dim3(1024), dim3(256), 0, stream>>>(hA, Wo, bo, out);
}